// Round 16
// baseline (203.154 us; speedup 1.0000x reference)
//
#include <hip/hip_runtime.h>

#define N_NODES 100000
#define NBKT 782              // ceil(100000/128) buckets of 128 dst nodes
#define EPB 2048              // edges per partition block (r15: 8192 gave <1 blk/CU)
#define SL_U 400000           // uints per fp8 y1 slice = N_NODES*4 (16B rows)

typedef unsigned int uint;
typedef unsigned short ushort;
typedef __attribute__((ext_vector_type(8))) short bf16x8;   // 8 bf16 (4 VGPRs)
typedef __attribute__((ext_vector_type(4))) float f32x4;    // MFMA acc
typedef __attribute__((ext_vector_type(2))) float f32x2;    // fp8 unpack pair

union FragU { uint4 u; bf16x8 b; };

// ---------- bf16 helpers ------------------------------------------------------
__device__ __forceinline__ uint pack_bf16_2(float a, float b) {
    uint ua = __float_as_uint(a), ub = __float_as_uint(b);
    ua += 0x7fff + ((ua >> 16) & 1);           // RNE
    ub += 0x7fff + ((ub >> 16) & 1);
    return (ua >> 16) | (ub & 0xffff0000u);
}

// ---------- edge-index access (handles int32 or raw int64 little-endian) ----
__device__ __forceinline__ int edge_at(const int* __restrict__ ei, int idx, int is64) {
    return is64 ? ei[2 * idx] : ei[idx];
}

// per-block dtype probe: 1 if int64 little-endian layout (all odd words zero)
__device__ __forceinline__ int block_probe_is64(const int* __restrict__ ei, int* sh) {
    int t = threadIdx.x;
    if (t == 0) *sh = 0;
    __syncthreads();
    int any = 0;
    for (int j = t; j < 4096; j += blockDim.x) any |= ei[2 * j + 1];
    if (any) atomicOr(sh, 1);
    __syncthreads();
    return (*sh == 0);
}

// ---------- phase A1: bucket histogram -> private slab; block 0 -> gflag -----
__global__ __launch_bounds__(256) void kA1(const int* __restrict__ ei, int E,
                                           int* __restrict__ slab,
                                           int* __restrict__ gflag) {
    __shared__ int h[NBKT];
    __shared__ int shp;
    int t = threadIdx.x;
    int is64 = block_probe_is64(ei, &shp);
    if (blockIdx.x == 0 && t == 0) gflag[0] = is64 ? 0 : 1;
    for (int i = t; i < NBKT; i += 256) h[i] = 0;
    __syncthreads();
    int base = blockIdx.x * EPB;
    int end = min(base + EPB, E);
    for (int e = base + t; e < end; e += 256) {
        int d = edge_at(ei, E + e, is64);
        atomicAdd(&h[d >> 7], 1);
    }
    __syncthreads();
    for (int i = t; i < NBKT; i += 256)
        slab[(size_t)blockIdx.x * NBKT + i] = h[i];
}

// ---------- phase A2a: column prefix-scan of slab (one wave per bucket) ------
// (r10 lesson: parallelize slab traversal across CUs, never one block.)
__global__ __launch_bounds__(256) void kA2a(int* __restrict__ slab, int PB,
                                            int* __restrict__ bkt_cnt) {
    int w = threadIdx.x >> 6;                 // wave in block (0..3)
    int l = threadIdx.x & 63;                 // lane
    int k = blockIdx.x * 4 + w;               // bucket column
    if (k >= NBKT) return;
    int carry = 0;
    for (int base = 0; base < PB; base += 64) {
        int row = base + l;
        int v = (row < PB) ? slab[(size_t)row * NBKT + k] : 0;
        int incl = v;
#pragma unroll
        for (int d = 1; d < 64; d <<= 1) {
            int y = __shfl_up(incl, d, 64);
            if (l >= d) incl += y;
        }
        if (row < PB) slab[(size_t)row * NBKT + k] = carry + incl - v;  // excl
        carry += __shfl(incl, 63, 64);
    }
    if (l == 0) bkt_cnt[k] = carry;
}

// ---------- phase A2b: exclusive scan of 782 bucket counts (1 block, LDS) ----
__global__ __launch_bounds__(1024) void kA2b(const int* __restrict__ bkt_cnt,
                                             int* __restrict__ bkt_off) {
    __shared__ int s[1024];
    int t = threadIdx.x;
    int v = (t < NBKT) ? bkt_cnt[t] : 0;
    s[t] = v;
    __syncthreads();
    for (int d = 1; d < 1024; d <<= 1) {
        int y = (t >= d) ? s[t - d] : 0;
        __syncthreads();
        s[t] += y;
        __syncthreads();
    }
    if (t < NBKT) bkt_off[t] = s[t] - v;       // exclusive
}

// ---------- phase A3: single-pass partition (bases precomputed, no cursors) --
__global__ __launch_bounds__(256) void kA3(const int* __restrict__ ei, int E,
                                           const int* __restrict__ gflag,
                                           const int* __restrict__ slab,
                                           const int* __restrict__ bkt_off,
                                           uint* __restrict__ bkt_data) {
    __shared__ int h[NBKT];                   // local rank cursor
    __shared__ int pre[NBKT];                 // global base for this block
    int t = threadIdx.x;
    int is64 = (gflag[0] == 0);
    for (int i = t; i < NBKT; i += 256) {
        h[i] = 0;
        pre[i] = bkt_off[i] + slab[(size_t)blockIdx.x * NBKT + i];
    }
    __syncthreads();
    int lo = blockIdx.x * EPB;
    int end = min(lo + EPB, E);
    for (int e = lo + t; e < end; e += 256) {
        int d = edge_at(ei, E + e, is64);
        int s = edge_at(ei, e, is64);
        int b = d >> 7;
        int r = atomicAdd(&h[b], 1);
        bkt_data[pre[b] + r] = ((uint)s << 7) | (uint)(d & 127);
    }
}

// ---------- phase B: per-bucket CSR build + degrees + dis + y2 zero ----------
__global__ __launch_bounds__(256) void kB(const uint* __restrict__ bkt_data,
                                          const int* __restrict__ bkt_off,
                                          const int* __restrict__ bkt_cnt,
                                          int* __restrict__ srcs,
                                          int* __restrict__ count,
                                          int* __restrict__ offs,
                                          float* __restrict__ dis,
                                          float* __restrict__ y2) {
    __shared__ int lc[128];    // local degree
    __shared__ int sc[128];    // inclusive scan
    __shared__ int lcur[128];  // local fill cursor
    int t = threadIdx.x;
    int b = blockIdx.x;
    {
        int zb = b * 1024;
        int ze = min(zb + 1024, N_NODES * 8);
        for (int i = zb + t; i < ze; i += 256) y2[i] = 0.0f;
    }
    if (t < 128) { lc[t] = 0; lcur[t] = 0; }
    __syncthreads();
    int start = bkt_off[b];
    int n = bkt_cnt[b];
    for (int i = t; i < n; i += 256)
        atomicAdd(&lc[bkt_data[start + i] & 127], 1);
    __syncthreads();
    if (t < 128) sc[t] = lc[t];
    __syncthreads();
    for (int d = 1; d < 128; d <<= 1) {
        int y = 0;
        if (t < 128 && t >= d) y = sc[t - d];
        __syncthreads();
        if (t < 128) sc[t] += y;
        __syncthreads();
    }
    if (t < 128) {
        int node = b * 128 + t;
        if (node < N_NODES) {
            int c = lc[t];
            count[node] = c;
            offs[node] = start + sc[t] - c;
            dis[node] = rsqrtf((float)c + 1.0f);
        }
    }
    __syncthreads();
    for (int i = t; i < n; i += 256) {
        uint rec = bkt_data[start + i];
        int dl = rec & 127;
        int r = atomicAdd(&lcur[dl], 1);
        srcs[start + (sc[dl] - lc[dl]) + r] = rec >> 7;
    }
}

// ---------- GEMM1 (MFMA bf16 -> fp8 store): y1s = e4m3((x@W1)*dis), 8 slices -
// Slice = 16 cols x 1B = 16B rows (one dwordx4 gather in agg1s).
// (r12: slice must fit 4MB L2 — 1.6MB. r9: no NT.)
__global__ __launch_bounds__(256) void k_gemm1(const float* __restrict__ x,
                                               const float* __restrict__ W,
                                               const float* __restrict__ dis,
                                               uint* __restrict__ y1s) {
    __shared__ uint4 WtA[2048];               // 32 KB
    char* wt = (char*)WtA;
    int t = threadIdx.x;

    const float4* W4 = (const float4*)W;
#pragma unroll
    for (int ii = 0; ii < 4; ++ii) {
        int tile = t + 256 * ii;              // 1024 (nq,kq) 4x4 tiles
        int nq = tile >> 5, kq = tile & 31;
        float4 r0 = W4[(4 * kq + 0) * 32 + nq];
        float4 r1 = W4[(4 * kq + 1) * 32 + nq];
        float4 r2 = W4[(4 * kq + 2) * 32 + nq];
        float4 r3 = W4[(4 * kq + 3) * 32 + nq];
        const float* p0 = (const float*)&r0;
        const float* p1 = (const float*)&r1;
        const float* p2 = (const float*)&r2;
        const float* p3 = (const float*)&r3;
#pragma unroll
        for (int cc = 0; cc < 4; ++cc) {
            int n = 4 * nq + cc;
            uint2 v;
            v.x = pack_bf16_2(p0[cc], p1[cc]);
            v.y = pack_bf16_2(p2[cc], p3[cc]);
            *(uint2*)(wt + n * 256 + (((kq >> 1) ^ (n & 7)) << 4) + ((kq & 1) << 3)) = v;
        }
    }
    __syncthreads();

    int w = t >> 6, lane = t & 63;
    int m = lane & 15, kg = lane >> 4;
    int row0 = blockIdx.x * 64 + 16 * w;

    int arow = row0 + m;
    bool av = arow < N_NODES;
    const float4* xr = (const float4*)(x + (size_t)arow * 128);
    float4 z4 = make_float4(0.f, 0.f, 0.f, 0.f);
    FragU af[4];
#pragma unroll
    for (int kf = 0; kf < 4; ++kf) {
        float4 g0 = av ? xr[8 * kf + 2 * kg]     : z4;
        float4 g1 = av ? xr[8 * kf + 2 * kg + 1] : z4;
        const float* a0 = (const float*)&g0;
        const float* a1 = (const float*)&g1;
        af[kf].u.x = pack_bf16_2(a0[0], a0[1]);
        af[kf].u.y = pack_bf16_2(a0[2], a0[3]);
        af[kf].u.z = pack_bf16_2(a1[0], a1[1]);
        af[kf].u.w = pack_bf16_2(a1[2], a1[3]);
    }

    int crow = row0 + 4 * kg;
    float dd[4];
#pragma unroll
    for (int rr = 0; rr < 4; ++rr)
        dd[rr] = (crow + rr < N_NODES) ? dis[crow + rr] : 0.0f;

    char* yb = (char*)y1s;
#pragma unroll
    for (int ct = 0; ct < 8; ++ct) {          // col-tile == slice (16 cols)
        f32x4 acc = {0.f, 0.f, 0.f, 0.f};
#pragma unroll
        for (int kf = 0; kf < 4; ++kf) {
            int n = 16 * ct + m;              // B col = lane&15
            bf16x8 bw = *(const bf16x8*)(wt + n * 256 + ((((kf << 2) | kg) ^ (n & 7)) << 4));
            acc = __builtin_amdgcn_mfma_f32_16x16x32_bf16(af[kf].b, bw, acc, 0, 0, 0);
        }
#pragma unroll
        for (int rr = 0; rr < 4; ++rr) {
            float v = acc[rr] * dd[rr];
            float p = __shfl_xor(v, 1, 64);   // partner col (odd)
            if (!(lane & 1)) {
                int grow = crow + rr;
                if (grow < N_NODES) {
                    uint pk = __builtin_amdgcn_cvt_pk_fp8_f32(v, p, 0, false);
                    *(ushort*)(yb + (size_t)ct * (SL_U * 4) + grow * 16 + m) = (ushort)pk;
                }
            }
        }
    }
}

// ---------- Aggregation 1 (8 fp8 slices) + partial GEMM2 ---------------------
// slice = blockIdx.x % 8. 8-lane group per node, EDGE-PER-LANE, 1-deep
// prefetch, PACKED f32x2 accumulate (v_pk_add_f32: 8 pk_add vs 16 v_add).
// (r15: trip count ~2/lane — no deeper pipelining; r9: no NT; r12: slice<4MB.)
__global__ __launch_bounds__(256) void k_agg1s(const uint* __restrict__ y1s,
                                               const int* __restrict__ srcs,
                                               const int* __restrict__ offs,
                                               const int* __restrict__ count,
                                               const float* __restrict__ dis,
                                               const float* __restrict__ b1,
                                               const float* __restrict__ W2,
                                               float* __restrict__ y2) {
    int t = threadIdx.x;
    int slice = blockIdx.x & 7;
    int nb = blockIdx.x >> 3;
    int g = t >> 3;                    // group 0..31
    int j = t & 7;                     // lane in group
    int d = nb * 32 + g;               // node (3125*32 == 100000)

    // W2 rows for this lane (fixed): rows slice*16+2j, slice*16+2j+1
    float w0[8], w1[8];
    const float* wr0 = W2 + (size_t)(slice * 16 + 2 * j) * 8;
#pragma unroll
    for (int c = 0; c < 8; ++c) { w0[c] = wr0[c]; w1[c] = wr0[8 + c]; }

    const uint4* ybase = (const uint4*)(y1s + (size_t)slice * SL_U);
    f32x2 acc2[8];                     // acc2[k] = cols {2k, 2k+1}
#pragma unroll
    for (int c = 0; c < 8; ++c) acc2[c] = (f32x2){0.f, 0.f};

#define ACCUM_Q(q)                                                             \
    do {                                                                       \
        acc2[0] += __builtin_amdgcn_cvt_pk_f32_fp8((q).x, false);              \
        acc2[1] += __builtin_amdgcn_cvt_pk_f32_fp8((q).x, true);               \
        acc2[2] += __builtin_amdgcn_cvt_pk_f32_fp8((q).y, false);              \
        acc2[3] += __builtin_amdgcn_cvt_pk_f32_fp8((q).y, true);               \
        acc2[4] += __builtin_amdgcn_cvt_pk_f32_fp8((q).z, false);              \
        acc2[5] += __builtin_amdgcn_cvt_pk_f32_fp8((q).z, true);               \
        acc2[6] += __builtin_amdgcn_cvt_pk_f32_fp8((q).w, false);              \
        acc2[7] += __builtin_amdgcn_cvt_pk_f32_fp8((q).w, true);               \
    } while (0)

    int st = offs[d], n = count[d];
    int i = j;
    if (i <= n) {                                // i==n -> self-loop (one lane)
        int sk = (i < n) ? srcs[st + i] : d;
        uint4 q = ybase[sk];
        for (i += 8; i <= n; i += 8) {
            int sk2 = (i < n) ? srcs[st + i] : d;
            uint4 qn = ybase[sk2];               // prefetch next (in flight)
            ACCUM_Q(q);
            q = qn;
        }
        ACCUM_Q(q);
    }
#undef ACCUM_Q

    float acc[16];
#pragma unroll
    for (int c = 0; c < 8; ++c) { acc[2 * c] = acc2[c][0]; acc[2 * c + 1] = acc2[c][1]; }

    // reduce-scatter: lane j ends with cols 2j (v2[0]) and 2j+1 (v2[1])
    int hi4 = (j >> 2) & 1, hi2 = (j >> 1) & 1, hi1 = j & 1;
    float v8[8];
#pragma unroll
    for (int c = 0; c < 8; ++c) {
        float keep = hi4 ? acc[c + 8] : acc[c];
        float send = hi4 ? acc[c] : acc[c + 8];
        v8[c] = keep + __shfl_xor(send, 4, 8);
    }
    float v4[4];
#pragma unroll
    for (int c = 0; c < 4; ++c) {
        float keep = hi2 ? v8[c + 4] : v8[c];
        float send = hi2 ? v8[c] : v8[c + 4];
        v4[c] = keep + __shfl_xor(send, 2, 8);
    }
    float v2[2];
#pragma unroll
    for (int c = 0; c < 2; ++c) {
        float keep = hi1 ? v4[c + 2] : v4[c];
        float send = hi1 ? v4[c] : v4[c + 2];
        v2[c] = keep + __shfl_xor(send, 1, 8);
    }

    float ddv = dis[d];
    float2 b = ((const float2*)b1)[slice * 8 + j];
    float h0 = fmaxf(fmaf(v2[0], ddv, b.x), 0.0f);
    float h1 = fmaxf(fmaf(v2[1], ddv, b.y), 0.0f);

    float p[8];
#pragma unroll
    for (int c = 0; c < 8; ++c) p[c] = h0 * w0[c] + h1 * w1[c];
    float q4[4];
#pragma unroll
    for (int c = 0; c < 4; ++c) {
        float keep = hi4 ? p[c + 4] : p[c];
        float send = hi4 ? p[c] : p[c + 4];
        q4[c] = keep + __shfl_xor(send, 4, 8);
    }
    float q2[2];
#pragma unroll
    for (int c = 0; c < 2; ++c) {
        float keep = hi2 ? q4[c + 2] : q4[c];
        float send = hi2 ? q4[c] : q4[c + 2];
        q2[c] = keep + __shfl_xor(send, 2, 8);
    }
    float keep = hi1 ? q2[1] : q2[0];
    float send = hi1 ? q2[0] : q2[1];
    float q = keep + __shfl_xor(send, 1, 8);   // class j

    atomicAdd(&y2[(size_t)d * 8 + j], q * ddv);
}

// ---------- Aggregation 2 (edge-per-lane) + bias + log_softmax -> out --------
__global__ __launch_bounds__(256) void k_agg2(const float* __restrict__ y2,
                                              const int* __restrict__ srcs,
                                              const int* __restrict__ offs,
                                              const int* __restrict__ count,
                                              const float* __restrict__ dis,
                                              const float* __restrict__ b2,
                                              float* __restrict__ out) {
    int t = threadIdx.x;
    int g = (blockIdx.x * 256 + t) >> 3;   // node
    int j = t & 7;                         // lane in group
    if (g >= N_NODES) return;
    const float4* yb = (const float4*)y2;
    float acc[8];
#pragma unroll
    for (int c = 0; c < 8; ++c) acc[c] = 0.0f;
    int st = offs[g], n = count[g];
    for (int i = j; i <= n; i += 8) {          // i==n -> self term (one lane)
        int sk = g;
        if (i < n) sk = srcs[st + i];
        float4 a = yb[(size_t)sk * 2];
        float4 b = yb[(size_t)sk * 2 + 1];
        acc[0] += a.x; acc[1] += a.y; acc[2] += a.z; acc[3] += a.w;
        acc[4] += b.x; acc[5] += b.y; acc[6] += b.z; acc[7] += b.w;
    }
    int hi4 = (j >> 2) & 1, hi2 = (j >> 1) & 1, hi1 = j & 1;
    float v4[4];
#pragma unroll
    for (int c = 0; c < 4; ++c) {
        float keep = hi4 ? acc[c + 4] : acc[c];
        float send = hi4 ? acc[c] : acc[c + 4];
        v4[c] = keep + __shfl_xor(send, 4, 8);
    }
    float v2[2];
#pragma unroll
    for (int c = 0; c < 2; ++c) {
        float keep = hi2 ? v4[c + 2] : v4[c];
        float send = hi2 ? v4[c] : v4[c + 2];
        v2[c] = keep + __shfl_xor(send, 2, 8);
    }
    float keep = hi1 ? v2[1] : v2[0];
    float send = hi1 ? v2[0] : v2[1];
    float q = keep + __shfl_xor(send, 1, 8);   // class j

    float o = fmaf(q, dis[g], b2[j]);
    float m = o;
#pragma unroll
    for (int k = 1; k < 8; k <<= 1) m = fmaxf(m, __shfl_xor(m, k, 64));
    float e = expf(o - m);
    float ssum = e;
#pragma unroll
    for (int k = 1; k < 8; k <<= 1) ssum += __shfl_xor(ssum, k, 64);
    out[(size_t)g * 8 + j] = (o - m) - logf(ssum);
}

// ---------- host launcher -----------------------------------------------------
extern "C" void kernel_launch(void* const* d_in, const int* in_sizes, int n_in,
                              void* d_out, int out_size, void* d_ws, size_t ws_size,
                              hipStream_t stream) {
    const float* x  = (const float*)d_in[0];
    const int*   ei = (const int*)d_in[1];
    const float* W1 = (const float*)d_in[2];
    const float* b1 = (const float*)d_in[3];
    const float* W2 = (const float*)d_in[4];
    const float* b2 = (const float*)d_in[5];
    float* out = (float*)d_out;
    const int E = in_sizes[1] / 2;     // logical edge count
    const int PB = (E + EPB - 1) / EPB;
    const int Epad = (E + 3) & ~3;
    int slabInts = (PB * NBKT + 3) & ~3;

    // workspace layout (all 16B-aligned)
    int*   slab     = (int*)d_ws;                      // PB*NBKT ints (~2.4MB)
    int*   bkt_cnt  = slab + slabInts;                 // 784 ints
    int*   bkt_off  = bkt_cnt + 784;                   // 784 ints
    int*   gflag    = bkt_off + 784;                   // 4 ints
    int*   count    = gflag + 4;                       // N ints
    int*   offs     = count + N_NODES;                 // N ints
    float* dis      = (float*)(offs + N_NODES);        // N floats
    uint*  bkt_data = (uint*)(dis + N_NODES);          // Epad uints
    int*   srcs     = (int*)(bkt_data + Epad);         // Epad ints
    uint*  y1s      = (uint*)(srcs + Epad);            // 8 slices * N*4 uints (fp8)
    float* y2       = (float*)(y1s + (size_t)8 * SL_U);   // N*8 floats

    kA1    <<<PB, 256, 0, stream>>>(ei, E, slab, gflag);
    kA2a   <<<(NBKT + 3) / 4, 256, 0, stream>>>(slab, PB, bkt_cnt);
    kA2b   <<<1, 1024, 0, stream>>>(bkt_cnt, bkt_off);
    kA3    <<<PB, 256, 0, stream>>>(ei, E, gflag, slab, bkt_off, bkt_data);
    kB     <<<NBKT, 256, 0, stream>>>(bkt_data, bkt_off, bkt_cnt, srcs, count, offs, dis, y2);

    k_gemm1<<<(N_NODES + 63) / 64, 256, 0, stream>>>(x, W1, dis, y1s);
    k_agg1s<<<8 * 3125, 256, 0, stream>>>(y1s, srcs, offs, count, dis, b1, W2, y2);
    k_agg2 <<<(N_NODES * 8 + 255) / 256, 256, 0, stream>>>(y2, srcs, offs, count, dis, b2, out);
}

// Round 17
// 195.854 us; speedup vs baseline: 1.0373x; 1.0373x over previous
//
#include <hip/hip_runtime.h>

#define N_NODES 100000
#define NBKT 782              // ceil(100000/128) buckets of 128 dst nodes
#define EPB 8192              // edges per partition block (r16: 2048 regressed — per-block fixed cost)
#define SL_U 400000           // uints per fp8 y1 slice = N_NODES*4 (16B rows)

typedef unsigned int uint;
typedef unsigned short ushort;
typedef __attribute__((ext_vector_type(8))) short bf16x8;   // 8 bf16 (4 VGPRs)
typedef __attribute__((ext_vector_type(4))) float f32x4;    // MFMA acc
typedef __attribute__((ext_vector_type(2))) float f32x2;    // fp8 unpack pair

union FragU { uint4 u; bf16x8 b; };

// ---------- bf16 helpers ------------------------------------------------------
__device__ __forceinline__ uint pack_bf16_2(float a, float b) {
    uint ua = __float_as_uint(a), ub = __float_as_uint(b);
    ua += 0x7fff + ((ua >> 16) & 1);           // RNE
    ub += 0x7fff + ((ub >> 16) & 1);
    return (ua >> 16) | (ub & 0xffff0000u);
}
__device__ __forceinline__ float bf_lo(uint u) { return __uint_as_float(u << 16); }
__device__ __forceinline__ float bf_hi(uint u) { return __uint_as_float(u & 0xffff0000u); }

// ---------- edge-index access (handles int32 or raw int64 little-endian) ----
__device__ __forceinline__ int edge_at(const int* __restrict__ ei, int idx, int is64) {
    return is64 ? ei[2 * idx] : ei[idx];
}

// per-block dtype probe: 1 if int64 little-endian layout (all odd words zero)
__device__ __forceinline__ int block_probe_is64(const int* __restrict__ ei, int* sh) {
    int t = threadIdx.x;
    if (t == 0) *sh = 0;
    __syncthreads();
    int any = 0;
    for (int j = t; j < 4096; j += blockDim.x) any |= ei[2 * j + 1];
    if (any) atomicOr(sh, 1);
    __syncthreads();
    return (*sh == 0);
}

// ---------- phase A1: bucket histogram -> private slab; block 0 -> gflag -----
__global__ __launch_bounds__(256) void kA1(const int* __restrict__ ei, int E,
                                           int* __restrict__ slab,
                                           int* __restrict__ gflag) {
    __shared__ int h[NBKT];
    __shared__ int shp;
    int t = threadIdx.x;
    int is64 = block_probe_is64(ei, &shp);
    if (blockIdx.x == 0 && t == 0) gflag[0] = is64 ? 0 : 1;
    for (int i = t; i < NBKT; i += 256) h[i] = 0;
    __syncthreads();
    int base = blockIdx.x * EPB;
    int end = min(base + EPB, E);
    for (int e = base + t; e < end; e += 256) {
        int d = edge_at(ei, E + e, is64);
        atomicAdd(&h[d >> 7], 1);
    }
    __syncthreads();
    for (int i = t; i < NBKT; i += 256)
        slab[(size_t)blockIdx.x * NBKT + i] = h[i];
}

// ---------- phase A2a: column prefix-scan of slab (one wave per bucket) ------
// (r10 lesson: parallelize slab traversal across CUs, never one block.)
__global__ __launch_bounds__(256) void kA2a(int* __restrict__ slab, int PB,
                                            int* __restrict__ bkt_cnt) {
    int w = threadIdx.x >> 6;                 // wave in block (0..3)
    int l = threadIdx.x & 63;                 // lane
    int k = blockIdx.x * 4 + w;               // bucket column
    if (k >= NBKT) return;
    int carry = 0;
    for (int base = 0; base < PB; base += 64) {
        int row = base + l;
        int v = (row < PB) ? slab[(size_t)row * NBKT + k] : 0;
        int incl = v;
#pragma unroll
        for (int d = 1; d < 64; d <<= 1) {
            int y = __shfl_up(incl, d, 64);
            if (l >= d) incl += y;
        }
        if (row < PB) slab[(size_t)row * NBKT + k] = carry + incl - v;  // excl
        carry += __shfl(incl, 63, 64);
    }
    if (l == 0) bkt_cnt[k] = carry;
}

// ---------- phase A2b: exclusive scan of 782 bucket counts (1 block, LDS) ----
__global__ __launch_bounds__(1024) void kA2b(const int* __restrict__ bkt_cnt,
                                             int* __restrict__ bkt_off) {
    __shared__ int s[1024];
    int t = threadIdx.x;
    int v = (t < NBKT) ? bkt_cnt[t] : 0;
    s[t] = v;
    __syncthreads();
    for (int d = 1; d < 1024; d <<= 1) {
        int y = (t >= d) ? s[t - d] : 0;
        __syncthreads();
        s[t] += y;
        __syncthreads();
    }
    if (t < NBKT) bkt_off[t] = s[t] - v;       // exclusive
}

// ---------- phase A3: single-pass partition (bases precomputed, no cursors) --
__global__ __launch_bounds__(256) void kA3(const int* __restrict__ ei, int E,
                                           const int* __restrict__ gflag,
                                           const int* __restrict__ slab,
                                           const int* __restrict__ bkt_off,
                                           uint* __restrict__ bkt_data) {
    __shared__ int h[NBKT];                   // local rank cursor
    __shared__ int pre[NBKT];                 // global base for this block
    int t = threadIdx.x;
    int is64 = (gflag[0] == 0);
    for (int i = t; i < NBKT; i += 256) {
        h[i] = 0;
        pre[i] = bkt_off[i] + slab[(size_t)blockIdx.x * NBKT + i];
    }
    __syncthreads();
    int lo = blockIdx.x * EPB;
    int end = min(lo + EPB, E);
    for (int e = lo + t; e < end; e += 256) {
        int d = edge_at(ei, E + e, is64);
        int s = edge_at(ei, e, is64);
        int b = d >> 7;
        int r = atomicAdd(&h[b], 1);
        bkt_data[pre[b] + r] = ((uint)s << 7) | (uint)(d & 127);
    }
}

// ---------- phase B: per-bucket CSR build + degrees + dis + y2 zero ----------
__global__ __launch_bounds__(256) void kB(const uint* __restrict__ bkt_data,
                                          const int* __restrict__ bkt_off,
                                          const int* __restrict__ bkt_cnt,
                                          int* __restrict__ srcs,
                                          int* __restrict__ count,
                                          int* __restrict__ offs,
                                          float* __restrict__ dis,
                                          float* __restrict__ y2) {
    __shared__ int lc[128];    // local degree
    __shared__ int sc[128];    // inclusive scan
    __shared__ int lcur[128];  // local fill cursor
    int t = threadIdx.x;
    int b = blockIdx.x;
    {
        int zb = b * 1024;
        int ze = min(zb + 1024, N_NODES * 8);
        for (int i = zb + t; i < ze; i += 256) y2[i] = 0.0f;
    }
    if (t < 128) { lc[t] = 0; lcur[t] = 0; }
    __syncthreads();
    int start = bkt_off[b];
    int n = bkt_cnt[b];
    for (int i = t; i < n; i += 256)
        atomicAdd(&lc[bkt_data[start + i] & 127], 1);
    __syncthreads();
    if (t < 128) sc[t] = lc[t];
    __syncthreads();
    for (int d = 1; d < 128; d <<= 1) {
        int y = 0;
        if (t < 128 && t >= d) y = sc[t - d];
        __syncthreads();
        if (t < 128) sc[t] += y;
        __syncthreads();
    }
    if (t < 128) {
        int node = b * 128 + t;
        if (node < N_NODES) {
            int c = lc[t];
            count[node] = c;
            offs[node] = start + sc[t] - c;
            dis[node] = rsqrtf((float)c + 1.0f);
        }
    }
    __syncthreads();
    for (int i = t; i < n; i += 256) {
        uint rec = bkt_data[start + i];
        int dl = rec & 127;
        int r = atomicAdd(&lcur[dl], 1);
        srcs[start + (sc[dl] - lc[dl]) + r] = rec >> 7;
    }
}

// ---------- GEMM1 (MFMA bf16 -> fp8 store): y1s = e4m3((x@W1)*dis), 8 slices -
// Slice = 16 cols x 1B = 16B rows (one dwordx4 gather in agg1s).
// (r12: slice must fit 4MB L2 — 1.6MB. r9: no NT.)
__global__ __launch_bounds__(256) void k_gemm1(const float* __restrict__ x,
                                               const float* __restrict__ W,
                                               const float* __restrict__ dis,
                                               uint* __restrict__ y1s) {
    __shared__ uint4 WtA[2048];               // 32 KB
    char* wt = (char*)WtA;
    int t = threadIdx.x;

    const float4* W4 = (const float4*)W;
#pragma unroll
    for (int ii = 0; ii < 4; ++ii) {
        int tile = t + 256 * ii;              // 1024 (nq,kq) 4x4 tiles
        int nq = tile >> 5, kq = tile & 31;
        float4 r0 = W4[(4 * kq + 0) * 32 + nq];
        float4 r1 = W4[(4 * kq + 1) * 32 + nq];
        float4 r2 = W4[(4 * kq + 2) * 32 + nq];
        float4 r3 = W4[(4 * kq + 3) * 32 + nq];
        const float* p0 = (const float*)&r0;
        const float* p1 = (const float*)&r1;
        const float* p2 = (const float*)&r2;
        const float* p3 = (const float*)&r3;
#pragma unroll
        for (int cc = 0; cc < 4; ++cc) {
            int n = 4 * nq + cc;
            uint2 v;
            v.x = pack_bf16_2(p0[cc], p1[cc]);
            v.y = pack_bf16_2(p2[cc], p3[cc]);
            *(uint2*)(wt + n * 256 + (((kq >> 1) ^ (n & 7)) << 4) + ((kq & 1) << 3)) = v;
        }
    }
    __syncthreads();

    int w = t >> 6, lane = t & 63;
    int m = lane & 15, kg = lane >> 4;
    int row0 = blockIdx.x * 64 + 16 * w;

    int arow = row0 + m;
    bool av = arow < N_NODES;
    const float4* xr = (const float4*)(x + (size_t)arow * 128);
    float4 z4 = make_float4(0.f, 0.f, 0.f, 0.f);
    FragU af[4];
#pragma unroll
    for (int kf = 0; kf < 4; ++kf) {
        float4 g0 = av ? xr[8 * kf + 2 * kg]     : z4;
        float4 g1 = av ? xr[8 * kf + 2 * kg + 1] : z4;
        const float* a0 = (const float*)&g0;
        const float* a1 = (const float*)&g1;
        af[kf].u.x = pack_bf16_2(a0[0], a0[1]);
        af[kf].u.y = pack_bf16_2(a0[2], a0[3]);
        af[kf].u.z = pack_bf16_2(a1[0], a1[1]);
        af[kf].u.w = pack_bf16_2(a1[2], a1[3]);
    }

    int crow = row0 + 4 * kg;
    float dd[4];
#pragma unroll
    for (int rr = 0; rr < 4; ++rr)
        dd[rr] = (crow + rr < N_NODES) ? dis[crow + rr] : 0.0f;

    char* yb = (char*)y1s;
#pragma unroll
    for (int ct = 0; ct < 8; ++ct) {          // col-tile == slice (16 cols)
        f32x4 acc = {0.f, 0.f, 0.f, 0.f};
#pragma unroll
        for (int kf = 0; kf < 4; ++kf) {
            int n = 16 * ct + m;              // B col = lane&15
            bf16x8 bw = *(const bf16x8*)(wt + n * 256 + ((((kf << 2) | kg) ^ (n & 7)) << 4));
            acc = __builtin_amdgcn_mfma_f32_16x16x32_bf16(af[kf].b, bw, acc, 0, 0, 0);
        }
#pragma unroll
        for (int rr = 0; rr < 4; ++rr) {
            float v = acc[rr] * dd[rr];
            float p = __shfl_xor(v, 1, 64);   // partner col (odd)
            if (!(lane & 1)) {
                int grow = crow + rr;
                if (grow < N_NODES) {
                    uint pk = __builtin_amdgcn_cvt_pk_fp8_f32(v, p, 0, false);
                    *(ushort*)(yb + (size_t)ct * (SL_U * 4) + grow * 16 + m) = (ushort)pk;
                }
            }
        }
    }
}

// ---------- Aggregation 1 (8 fp8 slices) + partial GEMM2 ---------------------
// slice = blockIdx.x % 8. 8-lane group per node, EDGE-PER-LANE, 1-deep
// prefetch, packed f32x2 accumulate. (~86us floor: r6/r7/r12/r14/r15 bracket.)
__global__ __launch_bounds__(256) void k_agg1s(const uint* __restrict__ y1s,
                                               const int* __restrict__ srcs,
                                               const int* __restrict__ offs,
                                               const int* __restrict__ count,
                                               const float* __restrict__ dis,
                                               const float* __restrict__ b1,
                                               const float* __restrict__ W2,
                                               float* __restrict__ y2) {
    int t = threadIdx.x;
    int slice = blockIdx.x & 7;
    int nb = blockIdx.x >> 3;
    int g = t >> 3;                    // group 0..31
    int j = t & 7;                     // lane in group
    int d = nb * 32 + g;               // node (3125*32 == 100000)

    // W2 rows for this lane (fixed): rows slice*16+2j, slice*16+2j+1
    float w0[8], w1[8];
    const float* wr0 = W2 + (size_t)(slice * 16 + 2 * j) * 8;
#pragma unroll
    for (int c = 0; c < 8; ++c) { w0[c] = wr0[c]; w1[c] = wr0[8 + c]; }

    const uint4* ybase = (const uint4*)(y1s + (size_t)slice * SL_U);
    f32x2 acc2[8];                     // acc2[k] = cols {2k, 2k+1}
#pragma unroll
    for (int c = 0; c < 8; ++c) acc2[c] = (f32x2){0.f, 0.f};

#define ACCUM_Q(q)                                                             \
    do {                                                                       \
        acc2[0] += __builtin_amdgcn_cvt_pk_f32_fp8((q).x, false);              \
        acc2[1] += __builtin_amdgcn_cvt_pk_f32_fp8((q).x, true);               \
        acc2[2] += __builtin_amdgcn_cvt_pk_f32_fp8((q).y, false);              \
        acc2[3] += __builtin_amdgcn_cvt_pk_f32_fp8((q).y, true);               \
        acc2[4] += __builtin_amdgcn_cvt_pk_f32_fp8((q).z, false);              \
        acc2[5] += __builtin_amdgcn_cvt_pk_f32_fp8((q).z, true);               \
        acc2[6] += __builtin_amdgcn_cvt_pk_f32_fp8((q).w, false);              \
        acc2[7] += __builtin_amdgcn_cvt_pk_f32_fp8((q).w, true);               \
    } while (0)

    int st = offs[d], n = count[d];
    int i = j;
    if (i <= n) {                                // i==n -> self-loop (one lane)
        int sk = (i < n) ? srcs[st + i] : d;
        uint4 q = ybase[sk];
        for (i += 8; i <= n; i += 8) {
            int sk2 = (i < n) ? srcs[st + i] : d;
            uint4 qn = ybase[sk2];               // prefetch next (in flight)
            ACCUM_Q(q);
            q = qn;
        }
        ACCUM_Q(q);
    }
#undef ACCUM_Q

    float acc[16];
#pragma unroll
    for (int c = 0; c < 8; ++c) { acc[2 * c] = acc2[c][0]; acc[2 * c + 1] = acc2[c][1]; }

    // reduce-scatter: lane j ends with cols 2j (v2[0]) and 2j+1 (v2[1])
    int hi4 = (j >> 2) & 1, hi2 = (j >> 1) & 1, hi1 = j & 1;
    float v8[8];
#pragma unroll
    for (int c = 0; c < 8; ++c) {
        float keep = hi4 ? acc[c + 8] : acc[c];
        float send = hi4 ? acc[c] : acc[c + 8];
        v8[c] = keep + __shfl_xor(send, 4, 8);
    }
    float v4[4];
#pragma unroll
    for (int c = 0; c < 4; ++c) {
        float keep = hi2 ? v8[c + 4] : v8[c];
        float send = hi2 ? v8[c] : v8[c + 4];
        v4[c] = keep + __shfl_xor(send, 2, 8);
    }
    float v2[2];
#pragma unroll
    for (int c = 0; c < 2; ++c) {
        float keep = hi1 ? v4[c + 2] : v4[c];
        float send = hi1 ? v4[c] : v4[c + 2];
        v2[c] = keep + __shfl_xor(send, 1, 8);
    }

    float ddv = dis[d];
    float2 b = ((const float2*)b1)[slice * 8 + j];
    float h0 = fmaxf(fmaf(v2[0], ddv, b.x), 0.0f);
    float h1 = fmaxf(fmaf(v2[1], ddv, b.y), 0.0f);

    float p[8];
#pragma unroll
    for (int c = 0; c < 8; ++c) p[c] = h0 * w0[c] + h1 * w1[c];
    float q4[4];
#pragma unroll
    for (int c = 0; c < 4; ++c) {
        float keep = hi4 ? p[c + 4] : p[c];
        float send = hi4 ? p[c] : p[c + 4];
        q4[c] = keep + __shfl_xor(send, 4, 8);
    }
    float q2[2];
#pragma unroll
    for (int c = 0; c < 2; ++c) {
        float keep = hi2 ? q4[c + 2] : q4[c];
        float send = hi2 ? q4[c] : q4[c + 2];
        q2[c] = keep + __shfl_xor(send, 2, 8);
    }
    float keep = hi1 ? q2[1] : q2[0];
    float send = hi1 ? q2[0] : q2[1];
    float q = keep + __shfl_xor(send, 1, 8);   // class j

    atomicAdd(&y2[(size_t)d * 8 + j], q * ddv);
}

// ---------- pack y2 fp32 -> bf16x8 rows (16B) for agg2's gathers -------------
__global__ __launch_bounds__(256) void k_pack(const float4* __restrict__ y2q,
                                              uint4* __restrict__ y2b) {
    int i = blockIdx.x * 256 + threadIdx.x;    // node
    if (i >= N_NODES) return;
    float4 a = y2q[2 * i], b = y2q[2 * i + 1];
    uint4 o;
    o.x = pack_bf16_2(a.x, a.y);
    o.y = pack_bf16_2(a.z, a.w);
    o.z = pack_bf16_2(b.x, b.y);
    o.w = pack_bf16_2(b.z, b.w);
    y2b[i] = o;
}

// ---------- Aggregation 2 (edge-per-lane, bf16 rows) + log_softmax -----------
// 1 dwordx4/edge (halved requests vs fp32 rows); y2b = 1.6MB, L2-resident
// on every XCD. Self-loop = virtual edge i==n.
__global__ __launch_bounds__(256) void k_agg2(const uint4* __restrict__ y2b,
                                              const int* __restrict__ srcs,
                                              const int* __restrict__ offs,
                                              const int* __restrict__ count,
                                              const float* __restrict__ dis,
                                              const float* __restrict__ b2,
                                              float* __restrict__ out) {
    int t = threadIdx.x;
    int g = (blockIdx.x * 256 + t) >> 3;   // node
    int j = t & 7;                         // lane in group
    if (g >= N_NODES) return;
    f32x2 acc2[4];
#pragma unroll
    for (int c = 0; c < 4; ++c) acc2[c] = (f32x2){0.f, 0.f};
    int st = offs[g], n = count[g];
    for (int i = j; i <= n; i += 8) {          // i==n -> self term (one lane)
        int sk = g;
        if (i < n) sk = srcs[st + i];
        uint4 q = y2b[sk];
        acc2[0] += (f32x2){bf_lo(q.x), bf_hi(q.x)};
        acc2[1] += (f32x2){bf_lo(q.y), bf_hi(q.y)};
        acc2[2] += (f32x2){bf_lo(q.z), bf_hi(q.z)};
        acc2[3] += (f32x2){bf_lo(q.w), bf_hi(q.w)};
    }
    float acc[8];
#pragma unroll
    for (int c = 0; c < 4; ++c) { acc[2 * c] = acc2[c][0]; acc[2 * c + 1] = acc2[c][1]; }

    // reduce-scatter 8 -> 1: lane j ends with class j
    int hi4 = (j >> 2) & 1, hi2 = (j >> 1) & 1, hi1 = j & 1;
    float v4[4];
#pragma unroll
    for (int c = 0; c < 4; ++c) {
        float keep = hi4 ? acc[c + 4] : acc[c];
        float send = hi4 ? acc[c] : acc[c + 4];
        v4[c] = keep + __shfl_xor(send, 4, 8);
    }
    float v2[2];
#pragma unroll
    for (int c = 0; c < 2; ++c) {
        float keep = hi2 ? v4[c + 2] : v4[c];
        float send = hi2 ? v4[c] : v4[c + 2];
        v2[c] = keep + __shfl_xor(send, 2, 8);
    }
    float keep = hi1 ? v2[1] : v2[0];
    float send = hi1 ? v2[0] : v2[1];
    float q = keep + __shfl_xor(send, 1, 8);   // class j

    float o = fmaf(q, dis[g], b2[j]);
    float m = o;
#pragma unroll
    for (int k = 1; k < 8; k <<= 1) m = fmaxf(m, __shfl_xor(m, k, 64));
    float e = expf(o - m);
    float ssum = e;
#pragma unroll
    for (int k = 1; k < 8; k <<= 1) ssum += __shfl_xor(ssum, k, 64);
    out[(size_t)g * 8 + j] = (o - m) - logf(ssum);
}

// ---------- host launcher -----------------------------------------------------
extern "C" void kernel_launch(void* const* d_in, const int* in_sizes, int n_in,
                              void* d_out, int out_size, void* d_ws, size_t ws_size,
                              hipStream_t stream) {
    const float* x  = (const float*)d_in[0];
    const int*   ei = (const int*)d_in[1];
    const float* W1 = (const float*)d_in[2];
    const float* b1 = (const float*)d_in[3];
    const float* W2 = (const float*)d_in[4];
    const float* b2 = (const float*)d_in[5];
    float* out = (float*)d_out;
    const int E = in_sizes[1] / 2;     // logical edge count
    const int PB = (E + EPB - 1) / EPB;
    const int Epad = (E + 3) & ~3;
    int slabInts = (PB * NBKT + 3) & ~3;

    // workspace layout (all 16B-aligned)
    int*   slab     = (int*)d_ws;                      // PB*NBKT ints
    int*   bkt_cnt  = slab + slabInts;                 // 784 ints
    int*   bkt_off  = bkt_cnt + 784;                   // 784 ints
    int*   gflag    = bkt_off + 784;                   // 4 ints
    int*   count    = gflag + 4;                       // N ints
    int*   offs     = count + N_NODES;                 // N ints
    float* dis      = (float*)(offs + N_NODES);        // N floats
    uint*  bkt_data = (uint*)(dis + N_NODES);          // Epad uints
    int*   srcs     = (int*)(bkt_data + Epad);         // Epad ints
    uint*  y1s      = (uint*)(srcs + Epad);            // 8 slices * N*4 uints (fp8)
    float* y2       = (float*)(y1s + (size_t)8 * SL_U);   // N*8 floats
    uint4* y2b      = (uint4*)(y2 + (size_t)N_NODES * 8); // N*16B bf16 rows

    kA1    <<<PB, 256, 0, stream>>>(ei, E, slab, gflag);
    kA2a   <<<(NBKT + 3) / 4, 256, 0, stream>>>(slab, PB, bkt_cnt);
    kA2b   <<<1, 1024, 0, stream>>>(bkt_cnt, bkt_off);
    kA3    <<<PB, 256, 0, stream>>>(ei, E, gflag, slab, bkt_off, bkt_data);
    kB     <<<NBKT, 256, 0, stream>>>(bkt_data, bkt_off, bkt_cnt, srcs, count, offs, dis, y2);

    k_gemm1<<<(N_NODES + 63) / 64, 256, 0, stream>>>(x, W1, dis, y1s);
    k_agg1s<<<8 * 3125, 256, 0, stream>>>(y1s, srcs, offs, count, dis, b1, W2, y2);
    k_pack <<<(N_NODES + 255) / 256, 256, 0, stream>>>((const float4*)y2, y2b);
    k_agg2 <<<(N_NODES * 8 + 255) / 256, 256, 0, stream>>>(y2b, srcs, offs, count, dis, b2, out);
}